// Round 4
// baseline (344.523 us; speedup 1.0000x reference)
//
#include <hip/hip_runtime.h>

#define BB   128
#define DD   128
#define OUTN 100000
#define KP1  4097              // K+1
#define TEMP 0.07f

#define JT     128             // j rows per gemm block
#define NJT    782             // ceil(OUTN / JT)
#define SCORES (2 * BB * KP1)  // 1,048,832 floats of score output
#define NROW   (OUTN * DD)     // 12,800,000 floats per memory
#define N1F4   (NROW / 4)      // 3,200,000 float4 per memory
#define NF4    (2 * N1F4)
#define NSCALE_BLK 4097        // 4097*256 == SCORES exactly
#define NCPB   4096            // copy blocks in finalize (small-ws path)

typedef float vfloat4 __attribute__((ext_vector_type(4)));

// ---------------------------------------------------------------------------
// prep: transpose z1 -> z1t[d][b] (into out[0..16384), overwritten later by
// the gather's score writes) and zero the 128 partial-sum buckets.
// ---------------------------------------------------------------------------
__global__ __launch_bounds__(256) void prep_kernel(
    const float* __restrict__ z1, float* __restrict__ z1t,
    float* __restrict__ part)
{
    const int bid = blockIdx.x;
    if (bid == 64) {
        if (threadIdx.x < 128) part[threadIdx.x] = 0.f;
        return;
    }
    const int e = bid * 256 + threadIdx.x;   // [0, 16384)
    const int d = e >> 7, b = e & 127;
    z1t[e] = z1[b * DD + d];                 // e == d*128 + b
}

// ---------------------------------------------------------------------------
// GEMM: S[j][b] = dot(mem[j], z1[b]) for all j, both memories.
// 256 threads, tile 128j x 128b, micro-tile 8j x 8b per thread.
// mem tile in LDS (64 KB, XOR-swizzled float4 columns: phys = c ^ (j>>3) ->
// conflict-free for the 4 ty-rows a wave reads). z1t read from global
// (64 KB, L1/L2-resident). If do_copy, staging also streams the mem tile to
// the output copy region via nontemporal stores (big-workspace path).
// ---------------------------------------------------------------------------
__global__ __launch_bounds__(256, 2) void gemm_kernel(
    const float* __restrict__ mem2, const float* __restrict__ mem3,
    const float* __restrict__ z1t,
    float* __restrict__ s2, float* __restrict__ s3,
    float* __restrict__ cpy2, float* __restrict__ cpy3, int do_copy)
{
    __shared__ vfloat4 tile[128 * 32];       // 64 KB
    const int t  = threadIdx.x;
    const int tx = t & 15;                   // b-quad: b = tx*4..+3 and +64
    const int ty = t >> 4;                   // j-group: j = ty*8..+7
    const long jt = (long)blockIdx.x * JT;
    const vfloat4* z1tf = (const vfloat4*)z1t;

    for (int m = 0; m < 2; ++m) {
        const vfloat4* mem = (const vfloat4*)(m ? mem3 : mem2);
        float* sd = m ? s3 : s2;
        vfloat4* cd = (vfloat4*)(m ? cpy3 : cpy2);
        if (m) __syncthreads();              // all reads of tile done

        // ---- stage 128x128 tile (coalesced), swizzled LDS, optional copy-out
        #pragma unroll
        for (int i = 0; i < 16; ++i) {
            const int e = i * 256 + t;       // [0, 4096)
            const int j = e >> 5, c = e & 31;
            const long gj = jt + j;
            vfloat4 v = {0.f, 0.f, 0.f, 0.f};
            if (gj < OUTN) v = mem[gj * 32 + c];
            tile[j * 32 + (c ^ (j >> 3))] = v;
            if (do_copy && gj < OUTN)
                __builtin_nontemporal_store(v, cd + gj * 32 + c);
        }
        __syncthreads();

        // ---- compute 8x8 micro-tile
        float acc[8][8];
        #pragma unroll
        for (int a = 0; a < 8; ++a)
            #pragma unroll
            for (int bbi = 0; bbi < 8; ++bbi) acc[a][bbi] = 0.f;

        for (int d4 = 0; d4 < 32; ++d4) {
            vfloat4 zA[4], zB[4];
            #pragma unroll
            for (int q = 0; q < 4; ++q) {
                zA[q] = z1tf[(d4 * 4 + q) * 32 + tx];        // b = tx*4..+3
                zB[q] = z1tf[(d4 * 4 + q) * 32 + 16 + tx];   // b = 64+tx*4..+3
            }
            #pragma unroll
            for (int h = 0; h < 2; ++h) {
                vfloat4 mj[4];
                #pragma unroll
                for (int r = 0; r < 4; ++r) {
                    const int j = ty * 8 + h * 4 + r;        // j>>3 == ty
                    mj[r] = tile[j * 32 + (d4 ^ ty)];
                }
                #pragma unroll
                for (int q = 0; q < 4; ++q)
                    #pragma unroll
                    for (int r = 0; r < 4; ++r) {
                        const float mv = mj[r][q];
                        #pragma unroll
                        for (int bbi = 0; bbi < 4; ++bbi) {
                            acc[h * 4 + r][bbi]     += mv * zA[q][bbi];
                            acc[h * 4 + r][4 + bbi] += mv * zB[q][bbi];
                        }
                    }
            }
        }

        // ---- store S tile (coalesced float4)
        #pragma unroll
        for (int jj = 0; jj < 8; ++jj) {
            const long gj = jt + ty * 8 + jj;
            if (gj < OUTN) {
                vfloat4 o0 = {acc[jj][0], acc[jj][1], acc[jj][2], acc[jj][3]};
                vfloat4 o1 = {acc[jj][4], acc[jj][5], acc[jj][6], acc[jj][7]};
                *(vfloat4*)(sd + gj * DD + tx * 4)      = o0;
                *(vfloat4*)(sd + gj * DD + 64 + tx * 4) = o1;
            }
        }
    }
}

// ---------------------------------------------------------------------------
// gather: s = exp(S[idx][b]/T) — 4-byte random reads from LLC-resident S.
// Writes unscaled scores + 64-bucket partial sums for Z.
// ---------------------------------------------------------------------------
__global__ __launch_bounds__(256) void gather_kernel(
    const float* __restrict__ S2, const float* __restrict__ S3,
    const int* __restrict__ y, const int* __restrict__ idx,
    float* __restrict__ out, float* __restrict__ part)
{
    const int b = blockIdx.y;
    const int k = blockIdx.x * 256 + threadIdx.x;
    float s2v = 0.f, s3v = 0.f;
    if (k < KP1) {
        const int j = (k == 0) ? y[b] : idx[b * KP1 + k];
        s2v = expf(S2[(size_t)j * DD + b] * (1.0f / TEMP));
        s3v = expf(S3[(size_t)j * DD + b] * (1.0f / TEMP));
        out[b * KP1 + k]            = s2v;
        out[BB * KP1 + b * KP1 + k] = s3v;
    }
    #pragma unroll
    for (int off = 32; off > 0; off >>= 1) {
        s2v += __shfl_xor(s2v, off);
        s3v += __shfl_xor(s3v, off);
    }
    __shared__ float w2s[4], w3s[4];
    const int wave = threadIdx.x >> 6;
    const int lane = threadIdx.x & 63;
    if (lane == 0) { w2s[wave] = s2v; w3s[wave] = s3v; }
    __syncthreads();
    if (threadIdx.x == 0) {
        const float t2 = w2s[0] + w2s[1] + w2s[2] + w2s[3];
        const float t3 = w3s[0] + w3s[1] + w3s[2] + w3s[3];
        const int slot = (blockIdx.y * gridDim.x + blockIdx.x) & 63;
        atomicAdd(&part[slot],      t2);
        atomicAdd(&part[64 + slot], t3);
    }
}

// ---------------------------------------------------------------------------
// finalize: blocks [0, 4097) scale scores by Z; blocks [4097, 4097+NCPB)
// stream-copy mem -> out regions (small-ws path only; overwrites S).
// ---------------------------------------------------------------------------
__global__ __launch_bounds__(256) void finalize_kernel(
    const float* __restrict__ mem2, const float* __restrict__ mem3,
    float* __restrict__ out, const float* __restrict__ part, int do_copy)
{
    if (blockIdx.x < NSCALE_BLK) {
        __shared__ float sc[2];
        if (threadIdx.x == 0) {
            float t2 = 0.f, t3 = 0.f;
            for (int i = 0; i < 64; ++i) { t2 += part[i]; t3 += part[64 + i]; }
            sc[0] = (float)((double)(BB * KP1) / ((double)OUTN * (double)t2));
            sc[1] = (float)((double)(BB * KP1) / ((double)OUTN * (double)t3));
        }
        __syncthreads();
        const int i = blockIdx.x * 256 + threadIdx.x;   // always < SCORES
        out[i] *= sc[(i < BB * KP1) ? 0 : 1];
        return;
    }
    if (!do_copy) return;
    const vfloat4* m2f = (const vfloat4*)mem2;
    const vfloat4* m3f = (const vfloat4*)mem3;
    vfloat4* dstf = (vfloat4*)(out + SCORES);
    for (int i = (blockIdx.x - NSCALE_BLK) * 256 + threadIdx.x; i < NF4;
         i += NCPB * 256) {
        const vfloat4 v = (i < N1F4) ? m2f[i] : m3f[i - N1F4];
        __builtin_nontemporal_store(v, dstf + i);
    }
}

// ---------------------------------------------------------------------------
// update: pos = 2*z - mem[y] (momentum = -1), L2-normalize, scatter.
// Runs last (after copy). Last-write-wins on duplicate y.
// ---------------------------------------------------------------------------
__global__ __launch_bounds__(64) void update_kernel(
    const float* __restrict__ z2,
    const float* __restrict__ z3,
    const float* __restrict__ mem2,
    const float* __restrict__ mem3,
    const int*   __restrict__ y,
    float* __restrict__ out2,
    float* __restrict__ out3)
{
    const int b    = blockIdx.x;
    const int lane = threadIdx.x;   // 0..63
    const int yb   = y[b];

    for (int bp = b + 1; bp < BB; ++bp)
        if (y[bp] == yb) return;    // a later b' overwrites this row

    const float2 m2 = *(const float2*)(mem2 + (size_t)yb * DD + 2 * lane);
    const float2 m3 = *(const float2*)(mem3 + (size_t)yb * DD + 2 * lane);
    const float2 a2 = *(const float2*)(z2 + b * DD + 2 * lane);
    const float2 a3 = *(const float2*)(z3 + b * DD + 2 * lane);

    float2 p2, p3;
    p2.x = 2.f * a2.x - m2.x;  p2.y = 2.f * a2.y - m2.y;
    p3.x = 2.f * a3.x - m3.x;  p3.y = 2.f * a3.y - m3.y;

    float ss2 = p2.x * p2.x + p2.y * p2.y;
    float ss3 = p3.x * p3.x + p3.y * p3.y;
    #pragma unroll
    for (int off = 32; off > 0; off >>= 1) {
        ss2 += __shfl_xor(ss2, off);
        ss3 += __shfl_xor(ss3, off);
    }
    const float inv2 = 1.f / sqrtf(ss2);
    const float inv3 = 1.f / sqrtf(ss3);

    float2 w2, w3;
    w2.x = p2.x * inv2;  w2.y = p2.y * inv2;
    w3.x = p3.x * inv3;  w3.y = p3.y * inv3;
    *(float2*)(out2 + (size_t)yb * DD + 2 * lane) = w2;
    *(float2*)(out3 + (size_t)yb * DD + 2 * lane) = w3;
}

// ---------------------------------------------------------------------------
extern "C" void kernel_launch(void* const* d_in, const int* in_sizes, int n_in,
                              void* d_out, int out_size, void* d_ws, size_t ws_size,
                              hipStream_t stream)
{
    const float* z1   = (const float*)d_in[0];
    const float* z2   = (const float*)d_in[1];
    const float* z3   = (const float*)d_in[2];
    const float* mem2 = (const float*)d_in[3];
    const float* mem3 = (const float*)d_in[4];
    const int*   y    = (const int*)d_in[5];
    const int*   idx  = (const int*)d_in[6];
    float*       out  = (float*)d_out;
    float*       part = (float*)d_ws;

    // Big workspace: S lives in ws, copy fuses into gemm staging.
    const bool big = ws_size >= ((size_t)2 * NROW + 256) * sizeof(float);
    float* S2 = big ? (part + 256) : (out + SCORES);
    float* S3 = S2 + NROW;
    float* z1t = out;                       // first 64 KB of score region

    // 1: transpose z1, zero part buckets
    prep_kernel<<<65, 256, 0, stream>>>(z1, z1t, part);

    // 2: dense scores GEMM (+ fused copy on big-ws path)
    gemm_kernel<<<NJT, 256, 0, stream>>>(mem2, mem3, z1t, S2, S3,
                                         out + SCORES, out + SCORES + NROW,
                                         big ? 1 : 0);

    // 3: gather + exp + partial sums (overwrites z1t region with scores)
    dim3 gg(17, BB);
    gather_kernel<<<gg, 256, 0, stream>>>(S2, S3, y, idx, out, part);

    // 4: scale scores by Z (+ copy mem -> out on small-ws path)
    finalize_kernel<<<NSCALE_BLK + (big ? 0 : NCPB), 256, 0, stream>>>(
        mem2, mem3, out, part, big ? 0 : 1);

    // 5: updated rows (after copy)
    update_kernel<<<BB, 64, 0, stream>>>(z2, z3, mem2, mem3, y,
                                         out + SCORES,
                                         out + SCORES + NROW);
}

// Round 5
// 279.975 us; speedup vs baseline: 1.2305x; 1.2305x over previous
//
#include <hip/hip_runtime.h>

#define BB   128
#define DD   128
#define OUTN 100000
#define KP1  4097          // K+1
#define TEMP 0.07f

#define NSB   8320         // score blocks: 65 k-chunks * 128 b   (65*64 >= 4097)
#define N1F4  3200000      // OUTN*DD/4  (float4 elements in one memory)
#define NF4   6400000      // both memories
#define CSTRIDE (NSB * 256)
#define SCORES (2 * BB * KP1)   // 1,048,832
#define NSCALE_BLK 4097    // 4097*256 == SCORES exactly

// native vector type usable with __builtin_nontemporal_store
typedef float vfloat4 __attribute__((ext_vector_type(4)));

// ---------------------------------------------------------------------------
// Fused kernel (identical hot path to the proven 118.7us version):
// coalesced gather+dot+exp (8 lanes per (b,k) pair) + streaming mem->out
// copy riding in the gather's latency stalls. Change vs R2: block partial
// sums go to PER-BLOCK slots (plain stores) so no workspace zeroing and no
// memset dispatch is needed.
// ---------------------------------------------------------------------------
__global__ __launch_bounds__(256) void fused_kernel(
    const float* __restrict__ z1,
    const float* __restrict__ mem2,
    const float* __restrict__ mem3,
    const int*   __restrict__ y,
    const int*   __restrict__ idx,
    float* __restrict__ out,     // s2 at [0, B*KP1), s3 at [B*KP1, 2*B*KP1)
    float* __restrict__ part)    // part[sb]=sum2, part[NSB+sb]=sum3
{
    const int sb    = blockIdx.x;
    const int b     = sb & (BB - 1);
    const int chunk = sb >> 7;              // 0..64
    const int tid   = threadIdx.x;
    const int g     = tid & 7;              // lane within 8-lane group
    const int grp   = tid >> 3;             // pair slot 0..31

    // z1 fragment for this lane: 16 consecutive floats at element g*16
    const float4* zz = (const float4*)(z1 + (size_t)b * DD + g * 16);
    const float4 z0 = zz[0], zv1 = zz[1], zv2 = zz[2], zv3 = zz[3];

    const int yb = y[b];

    float acc2 = 0.f, acc3 = 0.f;

    for (int it = 0; it < 2; ++it) {
        const int k = chunk * 64 + it * 32 + grp;
        const bool valid = (k < KP1);
        int j = 0;
        if (valid) j = (k == 0) ? yb : idx[b * KP1 + k];

        const float4* r2 = (const float4*)(mem2 + (size_t)j * DD + g * 16);
        const float4* r3 = (const float4*)(mem3 + (size_t)j * DD + g * 16);
        const float4 a0 = r2[0], a1 = r2[1], a2 = r2[2], a3 = r2[3];
        const float4 c0 = r3[0], c1 = r3[1], c2 = r3[2], c3 = r3[3];

        float d2 = a0.x*z0.x  + a0.y*z0.y  + a0.z*z0.z  + a0.w*z0.w
                 + a1.x*zv1.x + a1.y*zv1.y + a1.z*zv1.z + a1.w*zv1.w
                 + a2.x*zv2.x + a2.y*zv2.y + a2.z*zv2.z + a2.w*zv2.w
                 + a3.x*zv3.x + a3.y*zv3.y + a3.z*zv3.z + a3.w*zv3.w;
        float d3 = c0.x*z0.x  + c0.y*z0.y  + c0.z*z0.z  + c0.w*z0.w
                 + c1.x*zv1.x + c1.y*zv1.y + c1.z*zv1.z + c1.w*zv1.w
                 + c2.x*zv2.x + c2.y*zv2.y + c2.z*zv2.z + c2.w*zv2.w
                 + c3.x*zv3.x + c3.y*zv3.y + c3.z*zv3.z + c3.w*zv3.w;

        // reduce across the 8-lane group (xor masks < 8 stay in-group)
        d2 += __shfl_xor(d2, 1);  d3 += __shfl_xor(d3, 1);
        d2 += __shfl_xor(d2, 2);  d3 += __shfl_xor(d3, 2);
        d2 += __shfl_xor(d2, 4);  d3 += __shfl_xor(d3, 4);

        if (valid && g == 0) {
            const float s2 = expf(d2 * (1.0f / TEMP));
            const float s3 = expf(d3 * (1.0f / TEMP));
            out[b * KP1 + k]            = s2;   // 8 leaders/wave write 8
            out[BB * KP1 + b * KP1 + k] = s3;   // consecutive floats: coalesced
            acc2 += s2;
            acc3 += s3;
        }
    }

    // ---- streaming copy slice (fills BW while other waves stall on gathers)
    {
        const vfloat4* m2f = (const vfloat4*)mem2;
        const vfloat4* m3f = (const vfloat4*)mem3;
        vfloat4* dstf = (vfloat4*)(out + SCORES);
        for (int i = sb * 256 + tid; i < NF4; i += CSTRIDE) {
            const vfloat4 v = (i < N1F4) ? m2f[i] : m3f[i - N1F4];
            __builtin_nontemporal_store(v, dstf + i);  // don't evict gather rows
        }
    }

    // ---- block partial sum of s (leaders live at lanes 0,8,...,56)
    acc2 += __shfl_xor(acc2, 8);   acc3 += __shfl_xor(acc3, 8);
    acc2 += __shfl_xor(acc2, 16);  acc3 += __shfl_xor(acc3, 16);
    acc2 += __shfl_xor(acc2, 32);  acc3 += __shfl_xor(acc3, 32);

    __shared__ float w2s[4], w3s[4];
    const int wave = tid >> 6;
    const int lane = tid & 63;
    if (lane == 0) { w2s[wave] = acc2; w3s[wave] = acc3; }
    __syncthreads();
    if (tid == 0) {
        part[sb]       = w2s[0] + w2s[1] + w2s[2] + w2s[3];   // plain store:
        part[NSB + sb] = w3s[0] + w3s[1] + w3s[2] + w3s[3];   // no memset needed
    }
}

// ---------------------------------------------------------------------------
// Finalize kernel, block zones:
//   [0, 4097):       parallel-reduce part -> Z, scale scores in place
//   [4097, 4225):    row update for b = blockIdx - 4097 (parallel dup check)
// ---------------------------------------------------------------------------
__global__ __launch_bounds__(256) void finalize_kernel(
    const float* __restrict__ z2,
    const float* __restrict__ z3,
    const float* __restrict__ mem2,
    const float* __restrict__ mem3,
    const int*   __restrict__ y,
    float* __restrict__ out,
    const float* __restrict__ part)
{
    const int t = threadIdx.x;

    if (blockIdx.x < NSCALE_BLK) {
        // ---- fully parallel reduction of the 2*NSB partial sums
        float t2 = 0.f, t3 = 0.f;
        for (int i = t; i < NSB; i += 256) {     // 33 coalesced iters
            t2 += part[i];
            t3 += part[NSB + i];
        }
        #pragma unroll
        for (int off = 32; off > 0; off >>= 1) {
            t2 += __shfl_xor(t2, off);
            t3 += __shfl_xor(t3, off);
        }
        __shared__ float r2[4], r3[4];
        if ((t & 63) == 0) { r2[t >> 6] = t2; r3[t >> 6] = t3; }
        __syncthreads();
        const float s2sum = r2[0] + r2[1] + r2[2] + r2[3];
        const float s3sum = r3[0] + r3[1] + r3[2] + r3[3];
        const float sc2 = (float)((double)(BB * KP1) / ((double)OUTN * (double)s2sum));
        const float sc3 = (float)((double)(BB * KP1) / ((double)OUTN * (double)s3sum));
        const int i = blockIdx.x * 256 + t;       // always < SCORES
        out[i] *= (i < BB * KP1) ? sc2 : sc3;
        return;
    }

    // ---- update zone: pos = 2*z - mem[y] (momentum = -1), L2-normalize
    const int b  = blockIdx.x - NSCALE_BLK;
    const int yb = y[b];

    __shared__ int dup;
    if (t == 0) dup = 0;
    __syncthreads();
    if (t > b && t < BB && y[t] == yb) dup = 1;   // parallel duplicate scan
    __syncthreads();
    if (dup) return;                              // a later b' overwrites row
    if (t >= 64) return;

    float* out2 = out + SCORES;
    float* out3 = out2 + OUTN * DD;

    const float2 m2 = *(const float2*)(mem2 + (size_t)yb * DD + 2 * t);
    const float2 m3 = *(const float2*)(mem3 + (size_t)yb * DD + 2 * t);
    const float2 a2 = *(const float2*)(z2 + b * DD + 2 * t);
    const float2 a3 = *(const float2*)(z3 + b * DD + 2 * t);

    float2 p2, p3;
    p2.x = 2.f * a2.x - m2.x;  p2.y = 2.f * a2.y - m2.y;
    p3.x = 2.f * a3.x - m3.x;  p3.y = 2.f * a3.y - m3.y;

    float ss2 = p2.x * p2.x + p2.y * p2.y;
    float ss3 = p3.x * p3.x + p3.y * p3.y;
    #pragma unroll
    for (int off = 32; off > 0; off >>= 1) {
        ss2 += __shfl_xor(ss2, off);
        ss3 += __shfl_xor(ss3, off);
    }
    const float inv2 = 1.f / sqrtf(ss2);
    const float inv3 = 1.f / sqrtf(ss3);

    float2 w2, w3;
    w2.x = p2.x * inv2;  w2.y = p2.y * inv2;
    w3.x = p3.x * inv3;  w3.y = p3.y * inv3;
    *(float2*)(out2 + (size_t)yb * DD + 2 * t) = w2;
    *(float2*)(out3 + (size_t)yb * DD + 2 * t) = w3;
}

// ---------------------------------------------------------------------------
extern "C" void kernel_launch(void* const* d_in, const int* in_sizes, int n_in,
                              void* d_out, int out_size, void* d_ws, size_t ws_size,
                              hipStream_t stream)
{
    const float* z1   = (const float*)d_in[0];
    const float* z2   = (const float*)d_in[1];
    const float* z3   = (const float*)d_in[2];
    const float* mem2 = (const float*)d_in[3];
    const float* mem3 = (const float*)d_in[4];
    const int*   y    = (const int*)d_in[5];
    const int*   idx  = (const int*)d_in[6];
    float*       out  = (float*)d_out;
    float*       part = (float*)d_ws;    // 2*NSB floats, fully overwritten

    // 1: coalesced gather scores + streaming copy (writes all part slots)
    fused_kernel<<<NSB, 256, 0, stream>>>(z1, mem2, mem3, y, idx, out, part);

    // 2: reduce Z + scale scores + scatter updated rows (block zones)
    finalize_kernel<<<NSCALE_BLK + BB, 256, 0, stream>>>(
        z2, z3, mem2, mem3, y, out, part);
}

// Round 6
// 275.700 us; speedup vs baseline: 1.2496x; 1.0155x over previous
//
#include <hip/hip_runtime.h>

#define BB   128
#define DD   128
#define OUTN 100000
#define KP1  4097          // K+1
#define TEMP 0.07f

#define NSB   8320         // logical score blocks: 65 k-chunks * 128 b
#define NPB   2080         // physical (persistent) blocks
#define ITERS 4            // NPB * ITERS == NSB exactly
#define N1F4  3200000      // OUTN*DD/4  (float4 elements in one memory)
#define NF4   6400000      // both memories
#define SCORES (2 * BB * KP1)   // 1,048,832
#define NSCALE_BLK 4097    // 4097*256 == SCORES exactly

// native vector type usable with __builtin_nontemporal_store
typedef float vfloat4 __attribute__((ext_vector_type(4)));

// ---------------------------------------------------------------------------
// Fused kernel, persistent-block version of the proven 118.7us hot loop.
// Each block owns 4 logical sb's (sb = bid + it*NPB). All 8 idx loads are
// hoisted to entry (one dependent-latency hop); row loads + dot + exp stay
// per-iteration exactly as the proven version. Epilogue (shared reduce +
// bucket atomics) runs ONCE per block instead of once per 64 scores, and
// there is no __syncthreads inside the work loop.
// ---------------------------------------------------------------------------
__global__ __launch_bounds__(256) void fused_kernel(
    const float* __restrict__ z1,
    const float* __restrict__ mem2,
    const float* __restrict__ mem3,
    const int*   __restrict__ y,
    const int*   __restrict__ idx,
    float* __restrict__ out,     // s2 at [0, B*KP1), s3 at [B*KP1, 2*B*KP1)
    float* __restrict__ part)    // part[0..63]=sum2 buckets, part[64..127]=sum3
{
    const int bid = blockIdx.x;
    const int tid = threadIdx.x;
    const int g   = tid & 7;              // lane within 8-lane group
    const int grp = tid >> 3;             // pair slot 0..31

    // ---- hoist all idx loads: one latency hop for the whole block's work
    int jj0[ITERS], jj1[ITERS];
    #pragma unroll
    for (int it = 0; it < ITERS; ++it) {
        const int sb    = bid + it * NPB;
        const int b     = sb & (BB - 1);
        const int chunk = sb >> 7;
        const int k0    = chunk * 64 + grp;
        const int k1    = k0 + 32;                 // never 0
        int j0 = 0, j1 = 0;
        if (k0 < KP1) j0 = (k0 == 0) ? y[b] : idx[b * KP1 + k0];
        if (k1 < KP1) j1 = idx[b * KP1 + k1];
        jj0[it] = j0;  jj1[it] = j1;
    }

    float acc2 = 0.f, acc3 = 0.f;

    #pragma unroll
    for (int it = 0; it < ITERS; ++it) {
        const int sb    = bid + it * NPB;
        const int b     = sb & (BB - 1);
        const int chunk = sb >> 7;

        // z1 fragment for this lane (L1/L2-hot after first round)
        const float4* zz = (const float4*)(z1 + (size_t)b * DD + g * 16);
        const float4 z0 = zz[0], zv1 = zz[1], zv2 = zz[2], zv3 = zz[3];

        #pragma unroll
        for (int p = 0; p < 2; ++p) {
            const int k     = chunk * 64 + p * 32 + grp;
            const bool valid = (k < KP1);
            const int j     = p ? jj1[it] : jj0[it];

            const float4* r2 = (const float4*)(mem2 + (size_t)j * DD + g * 16);
            const float4* r3 = (const float4*)(mem3 + (size_t)j * DD + g * 16);
            const float4 a0 = r2[0], a1 = r2[1], a2 = r2[2], a3 = r2[3];
            const float4 c0 = r3[0], c1 = r3[1], c2 = r3[2], c3 = r3[3];

            float d2 = a0.x*z0.x  + a0.y*z0.y  + a0.z*z0.z  + a0.w*z0.w
                     + a1.x*zv1.x + a1.y*zv1.y + a1.z*zv1.z + a1.w*zv1.w
                     + a2.x*zv2.x + a2.y*zv2.y + a2.z*zv2.z + a2.w*zv2.w
                     + a3.x*zv3.x + a3.y*zv3.y + a3.z*zv3.z + a3.w*zv3.w;
            float d3 = c0.x*z0.x  + c0.y*z0.y  + c0.z*z0.z  + c0.w*z0.w
                     + c1.x*zv1.x + c1.y*zv1.y + c1.z*zv1.z + c1.w*zv1.w
                     + c2.x*zv2.x + c2.y*zv2.y + c2.z*zv2.z + c2.w*zv2.w
                     + c3.x*zv3.x + c3.y*zv3.y + c3.z*zv3.z + c3.w*zv3.w;

            // reduce across the 8-lane group
            d2 += __shfl_xor(d2, 1);  d3 += __shfl_xor(d3, 1);
            d2 += __shfl_xor(d2, 2);  d3 += __shfl_xor(d3, 2);
            d2 += __shfl_xor(d2, 4);  d3 += __shfl_xor(d3, 4);

            if (valid && g == 0) {
                const float s2 = expf(d2 * (1.0f / TEMP));
                const float s3 = expf(d3 * (1.0f / TEMP));
                out[b * KP1 + k]            = s2;   // 8 leaders/wave write 8
                out[BB * KP1 + b * KP1 + k] = s3;   // consecutive floats
                acc2 += s2;
                acc3 += s3;
            }
        }
    }

    // ---- streaming copy slice (fills BW while other waves stall on gathers)
    {
        const vfloat4* m2f = (const vfloat4*)mem2;
        const vfloat4* m3f = (const vfloat4*)mem3;
        vfloat4* dstf = (vfloat4*)(out + SCORES);
        for (int i = bid * 256 + tid; i < NF4; i += NPB * 256) {
            const vfloat4 v = (i < N1F4) ? m2f[i] : m3f[i - N1F4];
            __builtin_nontemporal_store(v, dstf + i);  // don't evict gather rows
        }
    }

    // ---- ONE epilogue per block: reduce leaders, bucket atomics
    acc2 += __shfl_xor(acc2, 8);   acc3 += __shfl_xor(acc3, 8);
    acc2 += __shfl_xor(acc2, 16);  acc3 += __shfl_xor(acc3, 16);
    acc2 += __shfl_xor(acc2, 32);  acc3 += __shfl_xor(acc3, 32);

    __shared__ float w2s[4], w3s[4];
    const int wave = tid >> 6;
    const int lane = tid & 63;
    if (lane == 0) { w2s[wave] = acc2; w3s[wave] = acc3; }
    __syncthreads();
    if (tid == 0) {
        const float t2 = w2s[0] + w2s[1] + w2s[2] + w2s[3];
        const float t3 = w3s[0] + w3s[1] + w3s[2] + w3s[3];
        const int slot = bid & 63;
        atomicAdd(&part[slot],      t2);
        atomicAdd(&part[64 + slot], t3);
    }
}

// ---------------------------------------------------------------------------
// Finalize kernel, block zones:
//   [0, 4097):       read 128 bucket sums (thread 0, L2-hot), scale scores
//   [4097, 4225):    row update for b = blockIdx - 4097 (parallel dup check)
// ---------------------------------------------------------------------------
__global__ __launch_bounds__(256) void finalize_kernel(
    const float* __restrict__ z2,
    const float* __restrict__ z3,
    const float* __restrict__ mem2,
    const float* __restrict__ mem3,
    const int*   __restrict__ y,
    float* __restrict__ out,
    const float* __restrict__ part)
{
    const int t = threadIdx.x;

    if (blockIdx.x < NSCALE_BLK) {
        __shared__ float sc[2];
        if (t == 0) {
            float t2 = 0.f, t3 = 0.f;
            for (int i = 0; i < 64; ++i) { t2 += part[i]; t3 += part[64 + i]; }
            sc[0] = (float)((double)(BB * KP1) / ((double)OUTN * (double)t2));
            sc[1] = (float)((double)(BB * KP1) / ((double)OUTN * (double)t3));
        }
        __syncthreads();
        const int i = blockIdx.x * 256 + t;       // always < SCORES
        out[i] *= sc[(i < BB * KP1) ? 0 : 1];
        return;
    }

    // ---- update zone: pos = 2*z - mem[y] (momentum = -1), L2-normalize
    const int b  = blockIdx.x - NSCALE_BLK;
    const int yb = y[b];

    __shared__ int dup;
    if (t == 0) dup = 0;
    __syncthreads();
    if (t > b && t < BB && y[t] == yb) dup = 1;   // parallel duplicate scan
    __syncthreads();
    if (dup) return;                              // a later b' overwrites row
    if (t >= 64) return;

    float* out2 = out + SCORES;
    float* out3 = out2 + OUTN * DD;

    const float2 m2 = *(const float2*)(mem2 + (size_t)yb * DD + 2 * t);
    const float2 m3 = *(const float2*)(mem3 + (size_t)yb * DD + 2 * t);
    const float2 a2 = *(const float2*)(z2 + b * DD + 2 * t);
    const float2 a3 = *(const float2*)(z3 + b * DD + 2 * t);

    float2 p2, p3;
    p2.x = 2.f * a2.x - m2.x;  p2.y = 2.f * a2.y - m2.y;
    p3.x = 2.f * a3.x - m3.x;  p3.y = 2.f * a3.y - m3.y;

    float ss2 = p2.x * p2.x + p2.y * p2.y;
    float ss3 = p3.x * p3.x + p3.y * p3.y;
    #pragma unroll
    for (int off = 32; off > 0; off >>= 1) {
        ss2 += __shfl_xor(ss2, off);
        ss3 += __shfl_xor(ss3, off);
    }
    const float inv2 = 1.f / sqrtf(ss2);
    const float inv3 = 1.f / sqrtf(ss3);

    float2 w2, w3;
    w2.x = p2.x * inv2;  w2.y = p2.y * inv2;
    w3.x = p3.x * inv3;  w3.y = p3.y * inv3;
    *(float2*)(out2 + (size_t)yb * DD + 2 * t) = w2;
    *(float2*)(out3 + (size_t)yb * DD + 2 * t) = w3;
}

// ---------------------------------------------------------------------------
extern "C" void kernel_launch(void* const* d_in, const int* in_sizes, int n_in,
                              void* d_out, int out_size, void* d_ws, size_t ws_size,
                              hipStream_t stream)
{
    const float* z1   = (const float*)d_in[0];
    const float* z2   = (const float*)d_in[1];
    const float* z3   = (const float*)d_in[2];
    const float* mem2 = (const float*)d_in[3];
    const float* mem3 = (const float*)d_in[4];
    const int*   y    = (const int*)d_in[5];
    const int*   idx  = (const int*)d_in[6];
    float*       out  = (float*)d_out;
    float*       part = (float*)d_ws;

    hipMemsetAsync(d_ws, 0, 128 * sizeof(float), stream);

    // 1: persistent-block gather scores + streaming copy
    fused_kernel<<<NPB, 256, 0, stream>>>(z1, mem2, mem3, y, idx, out, part);

    // 2: scale scores by Z + scatter updated rows (block zones)
    finalize_kernel<<<NSCALE_BLK + BB, 256, 0, stream>>>(
        z2, z3, mem2, mem3, y, out, part);
}